// Round 5
// baseline (857.908 us; speedup 1.0000x reference)
//
#include <hip/hip_runtime.h>

#define IMG_W 1024
#define SLICE 1048576   // 1024*1024, one (n,c) plane
#define INF_F __builtin_huge_valf()
#define WS_PART_FLOATS (12 * 1024 * 289)   // phase-1 partials [plane][bx*32+by][k]

// ---- DPP wave64 sum: row_shr/row_bcast chain, total lands in lane 63.
template <int CTRL>
__device__ __forceinline__ float dpp_add_step(float x) {
    int m = __builtin_amdgcn_update_dpp(0, __builtin_bit_cast(int, x), CTRL, 0xf, 0xf, true);
    return x + __builtin_bit_cast(float, m);
}
__device__ __forceinline__ float wave_sum63(float x) {
    x = dpp_add_step<0x111>(x);  // row_shr:1
    x = dpp_add_step<0x112>(x);  // row_shr:2
    x = dpp_add_step<0x114>(x);  // row_shr:4
    x = dpp_add_step<0x118>(x);  // row_shr:8
    x = dpp_add_step<0x142>(x);  // row_bcast:15
    x = dpp_add_step<0x143>(x);  // row_bcast:31
    return x;                    // lane 63 holds the wave total
}

// ============================================================================
// L0 phase 1: R3 float4/fabs body (v_add with abs modifier folds), plus an
// XCD-aware 1D grid swizzle: all 32 tx of one (byq,plane) group land on the
// same XCD (bid%8 round-robin heuristic) so the group's ref row stays in L2.
// ============================================================================
__global__ __launch_bounds__(512, 4) void hbma_l0_phase1(const float* __restrict__ ref,
                                                         const float* __restrict__ tgt,
                                                         float* __restrict__ part) {
    const int bid   = blockIdx.x;          // 0..1535
    const int slot  = bid & 7;             // XCD slot under %8 round-robin
    const int j     = bid >> 3;            // 0..191
    const int group = slot * 6 + (j >> 5); // 0..47 : 6 groups per XCD
    const int tx    = j & 31;              // target block row 0..31
    const int byq   = group & 3;           // by quarter
    const int plane = group >> 2;          // 0..11

    const int t = threadIdx.x;
    const int lane = t & 63, w = t >> 6;
    const int by0 = byq * 8;
    const int by  = by0 + w;

    __shared__ float tile[16 * 1024];   // 16 block-plane slices of the target row (64 KB)

    const int prow = lane >> 3;        // rows prow+8i
    const int pcol = (lane & 7) << 2;  // cols pcol..pcol+3

    const float* tgt_p = tgt + (size_t)plane * SLICE;
    const float* ref_p = ref + (size_t)plane * SLICE;

    for (int batch = 0; batch < 2; ++batch) {
        const int tyBase = (batch == 0) ? (by0 - 8) : by0;
        const int dyLo   = (batch == 0) ? -8 : 0;
        const int dyHi   = (batch == 0) ? -1 : 8;

        __syncthreads();   // previous batch fully consumed
        for (int idx = t; idx < 16 * 256; idx += 512) {
            const int jj = idx >> 8;
            const int ty = tyBase + jj;
            if ((unsigned)ty < 32u) {
                const int ww = idx & 255;
                const int rr = ww >> 3;
                const int cc = (ww & 7) << 2;
                *(float4*)&tile[jj * 1024 + rr * 32 + cc] =
                    *(const float4*)(tgt_p + (size_t)(tx * 32 + rr) * IMG_W + ty * 32 + cc);
            }
        }
        __syncthreads();

        for (int dxg = 0; dxg < 5; ++dxg) {
            float4 rf[4][4];
            bool rvalid[4];
            #pragma unroll
            for (int r = 0; r < 4; ++r) {
                const int di = dxg * 4 + r;
                const int bx = tx - (di - 8);
                rvalid[r] = (di <= 16) && ((unsigned)bx < 32u);
                if (rvalid[r]) {
                    const float* rb = ref_p + (size_t)(bx * 32 + prow) * IMG_W + by * 32 + pcol;
                    #pragma unroll
                    for (int i = 0; i < 4; ++i)
                        rf[r][i] = *(const float4*)(rb + (size_t)i * 8 * IMG_W);
                }
            }
            for (int dy = dyLo; dy <= dyHi; ++dy) {
                const int ty = by + dy;
                if ((unsigned)ty >= 32u) continue;      // wave-uniform
                const int tbase = (ty - tyBase) * 1024 + prow * 32 + pcol;
                float4 tv[4];
                #pragma unroll
                for (int i = 0; i < 4; ++i)
                    tv[i] = *(const float4*)&tile[tbase + i * 256];
                #pragma unroll
                for (int r = 0; r < 4; ++r) {
                    if (!rvalid[r]) continue;           // wave-uniform
                    float4 a = {0.f, 0.f, 0.f, 0.f};
                    #pragma unroll
                    for (int i = 0; i < 4; ++i) {
                        a.x += __builtin_fabsf(rf[r][i].x - tv[i].x);
                        a.y += __builtin_fabsf(rf[r][i].y - tv[i].y);
                        a.z += __builtin_fabsf(rf[r][i].z - tv[i].z);
                        a.w += __builtin_fabsf(rf[r][i].w - tv[i].w);
                    }
                    const float s = wave_sum63((a.x + a.y) + (a.z + a.w));
                    if (lane == 63) {
                        const int di = dxg * 4 + r;
                        const int bx = tx - (di - 8);
                        part[((size_t)plane * 1024 + bx * 32 + by) * 289 + di * 17 + (dy + 8)] = s;
                    }
                }
            }
        }
    }
}

// ============================================================================
// L0 phase 2: sum 12 plane-partials, first-min argmin over k (lex (dx,dy)).
// ============================================================================
__global__ __launch_bounds__(64) void hbma_l0_phase2(const float* __restrict__ part,
                                                     int2* __restrict__ best0) {
    const int by = blockIdx.x;
    const int bx = blockIdx.y;
    const int t = threadIdx.x;

    float bc = INF_F; int bk = 1 << 30;
    for (int k = t; k < 289; k += 64) {
        const int dx = k / 17 - 8, dy = k % 17 - 8;
        const int tx = bx + dx,    ty = by + dy;
        if ((unsigned)tx < 32u && (unsigned)ty < 32u) {
            float c = 0.f;
            #pragma unroll
            for (int p = 0; p < 12; ++p)
                c += part[((size_t)p * 1024 + bx * 32 + by) * 289 + k];
            if (c < bc) { bc = c; bk = k; }   // ascending k -> first-min kept
        }
    }
    #pragma unroll
    for (int o = 32; o > 0; o >>= 1) {
        const float oc = __shfl_down(bc, o, 64);
        const int   ok = __shfl_down(bk, o, 64);
        if (oc < bc || (oc == bc && ok < bk)) { bc = oc; bk = ok; }
    }
    if (t == 0) best0[bx * 32 + by] = make_int2(bx + bk / 17 - 8, by + bk % 17 - 8);
}

// ============================================================================
// L1: one WG (512 thr = 8 waves) per PARENT. Wave (wc,kh): wc = plane-owner
// (planes {wc,wc+4,wc+8}), kh = candidate half (k<41 / k>=41). Halved per-wave
// iteration count + depth-2 register prefetch -> ~2x more lines in flight.
// ============================================================================
__global__ __launch_bounds__(512) void hbma_l1(const float* __restrict__ ref,
                                               const float* __restrict__ tgt,
                                               const int2* __restrict__ best0,
                                               float* __restrict__ out) {
    const int pby = blockIdx.x;  // 0..31
    const int pbx = blockIdx.y;  // 0..31
    const int t = threadIdx.x;
    const int lane = t & 63, w = t >> 6;   // 8 waves
    const int wc = w & 3;                  // plane-owner 0..3
    const int kh = w >> 2;                 // candidate half 0..1

    __shared__ float partials[4][81][4];   // [child][k][plane-owner]
    __shared__ int2 sbest[4];

    const int2 pb = best0[pbx * 32 + pby];
    const int cx = 2 * pb.x, cy = 2 * pb.y;

    // lane footprint: planes {wc+4i}, 16x16 slice, float4 per lane
    int off[3];
    #pragma unroll
    for (int i = 0; i < 3; ++i)
        off[i] = (wc + 4 * i) * SLICE + (lane >> 2) * IMG_W + ((lane & 3) << 2);

    int cbase[4];
    float4 rf[4][3];
    #pragma unroll
    for (int c = 0; c < 4; ++c) {
        const int bx = 2 * pbx + (c >> 1), by = 2 * pby + (c & 1);
        cbase[c] = (bx * 16) * IMG_W + by * 16;
        #pragma unroll
        for (int i = 0; i < 3; ++i)
            rf[c][i] = *(const float4*)(ref + cbase[c] + off[i]);
    }

    auto cand_base = [&](int k) -> const float* {
        int tx = cx + k / 9 - 4;
        int ty = cy + k % 9 - 4;
        tx = min(max(tx, 0), 63);
        ty = min(max(ty, 0), 63);
        return tgt + (tx * 16) * IMG_W + ty * 16;
    };

    const int kbeg = kh ? 41 : 0;
    const int kend = kh ? 81 : 41;

    // depth-2 prefetch pipeline
    float4 buf[2][3];
    {
        const float* b0 = cand_base(kbeg);
        const float* b1 = cand_base(min(kbeg + 1, kend - 1));
        #pragma unroll
        for (int i = 0; i < 3; ++i) buf[0][i] = *(const float4*)(b0 + off[i]);
        #pragma unroll
        for (int i = 0; i < 3; ++i) buf[1][i] = *(const float4*)(b1 + off[i]);
    }

    for (int k = kbeg; k < kend; ++k) {
        const int p = (k - kbeg) & 1;
        float4 tv[3];
        #pragma unroll
        for (int i = 0; i < 3; ++i) tv[i] = buf[p][i];
        // refill slot p with candidate k+2 (stays in flight through the compute)
        {
            const float* tb = cand_base(min(k + 2, kend - 1));
            #pragma unroll
            for (int i = 0; i < 3; ++i) buf[p][i] = *(const float4*)(tb + off[i]);
        }
        const int tx = cx + k / 9 - 4;
        const int ty = cy + k % 9 - 4;
        const bool valid = ((unsigned)tx < 64u) && ((unsigned)ty < 64u);

        #pragma unroll
        for (int c = 0; c < 4; ++c) {
            float4 a = {0.f, 0.f, 0.f, 0.f};
            #pragma unroll
            for (int i = 0; i < 3; ++i) {
                a.x += __builtin_fabsf(rf[c][i].x - tv[i].x);
                a.y += __builtin_fabsf(rf[c][i].y - tv[i].y);
                a.z += __builtin_fabsf(rf[c][i].z - tv[i].z);
                a.w += __builtin_fabsf(rf[c][i].w - tv[i].w);
            }
            const float s = wave_sum63((a.x + a.y) + (a.z + a.w));
            if (lane == 63) partials[c][k][wc] = valid ? s : INF_F;
        }
    }
    __syncthreads();

    // waves 0..3: argmin for child w (first-min over ascending k)
    if (w < 4) {
        const int c = w;
        float bc = INF_F; int bk = 1 << 30;
        for (int k = lane; k < 81; k += 64) {
            const float4 p4 = *(const float4*)&partials[c][k][0];
            const float cost = (p4.x + p4.y) + (p4.z + p4.w);
            if (cost < bc) { bc = cost; bk = k; }
        }
        #pragma unroll
        for (int o = 32; o > 0; o >>= 1) {
            const float oc = __shfl_down(bc, o, 64);
            const int   ok = __shfl_down(bk, o, 64);
            if (oc < bc || (oc == bc && ok < bk)) { bc = oc; bk = ok; }
        }
        if (lane == 0) sbest[c] = make_int2(cx + bk / 9 - 4, cy + bk % 9 - 4);
    }
    __syncthreads();

    // motion vectors: out[0..32767] as [N=4][2][64][64] (same for all n)
    if (t < 32) {
        const int c = t >> 3, n = (t >> 1) & 3, ch = t & 1;
        const int bx = 2 * pbx + (c >> 1), by = 2 * pby + (c & 1);
        const int2 fb = sbest[c];
        out[((n * 2 + ch) * 64 + bx) * 64 + by] = (ch == 0) ? (float)(fb.x - bx) : (float)(fb.y - by);
    }

    // predicted frame gather for all 4 children (768 float4s per child, 512 thr)
    float* pred = out + 32768;
    for (int idx = t; idx < 768; idx += 512) {
        const int nc = idx >> 6;
        const int ww = idx & 63;
        const int o = nc * SLICE + (ww >> 2) * IMG_W + ((ww & 3) << 2);
        #pragma unroll
        for (int c = 0; c < 4; ++c) {
            const int2 fb = sbest[c];
            *(float4*)(pred + cbase[c] + o) =
                *(const float4*)(tgt + (fb.x * 16) * IMG_W + fb.y * 16 + o);
        }
    }
}

extern "C" void kernel_launch(void* const* d_in, const int* in_sizes, int n_in,
                              void* d_out, int out_size, void* d_ws, size_t ws_size,
                              hipStream_t stream) {
    const float* ref = (const float*)d_in[0];
    const float* tgt = (const float*)d_in[1];
    float* out = (float*)d_out;

    float* part  = (float*)d_ws;                                      // 14.2 MB
    int2*  best0 = (int2*)((char*)d_ws + (size_t)WS_PART_FLOATS * 4); // 8 KB

    hbma_l0_phase1<<<dim3(1536), 512, 0, stream>>>(ref, tgt, part);
    hbma_l0_phase2<<<dim3(32, 32), 64, 0, stream>>>(part, best0);
    hbma_l1<<<dim3(32, 32), 512, 0, stream>>>(ref, tgt, best0, out);
}

// Round 6
// 550.790 us; speedup vs baseline: 1.5576x; 1.5576x over previous
//
#include <hip/hip_runtime.h>

#define IMG_W 1024
#define SLICE 1048576   // 1024*1024, one (n,c) plane
#define INF_F __builtin_huge_valf()
#define WS_PART_FLOATS (12 * 1024 * 289)   // phase-1 partials [plane][bx*32+by][k]

// ---- DPP wave64 sum: row_shr/row_bcast chain, total lands in lane 63.
template <int CTRL>
__device__ __forceinline__ float dpp_add_step(float x) {
    int m = __builtin_amdgcn_update_dpp(0, __builtin_bit_cast(int, x), CTRL, 0xf, 0xf, true);
    return x + __builtin_bit_cast(float, m);
}
__device__ __forceinline__ float wave_sum63(float x) {
    x = dpp_add_step<0x111>(x);  // row_shr:1
    x = dpp_add_step<0x112>(x);  // row_shr:2
    x = dpp_add_step<0x114>(x);  // row_shr:4
    x = dpp_add_step<0x118>(x);  // row_shr:8
    x = dpp_add_step<0x142>(x);  // row_bcast:15
    x = dpp_add_step<0x143>(x);  // row_bcast:31
    return x;                    // lane 63 holds the wave total
}

// ============================================================================
// L0 phase 1 (exact R3 structure — best measured: 264 us, VALU-bound).
// Grid (tx=32, byq=4, plane=12), 512 threads = 8 waves; wave w owns by=byq*8+w.
// ============================================================================
__global__ __launch_bounds__(512, 4) void hbma_l0_phase1(const float* __restrict__ ref,
                                                         const float* __restrict__ tgt,
                                                         float* __restrict__ part) {
    const int tx    = blockIdx.x;   // target block row 0..31
    const int byq   = blockIdx.y;   // by quarter 0..3
    const int plane = blockIdx.z;   // 0..11
    const int t = threadIdx.x;
    const int lane = t & 63, w = t >> 6;
    const int by0 = byq * 8;
    const int by  = by0 + w;

    __shared__ float tile[16 * 1024];   // 16 block-plane slices of the target row (64 KB)

    const int prow = lane >> 3;        // rows prow+8i
    const int pcol = (lane & 7) << 2;  // cols pcol..pcol+3

    const float* tgt_p = tgt + (size_t)plane * SLICE;
    const float* ref_p = ref + (size_t)plane * SLICE;

    for (int batch = 0; batch < 2; ++batch) {
        const int tyBase = (batch == 0) ? (by0 - 8) : by0;
        const int dyLo   = (batch == 0) ? -8 : 0;
        const int dyHi   = (batch == 0) ? -1 : 8;

        __syncthreads();   // previous batch fully consumed
        for (int idx = t; idx < 16 * 256; idx += 512) {
            const int jj = idx >> 8;
            const int ty = tyBase + jj;
            if ((unsigned)ty < 32u) {
                const int ww = idx & 255;
                const int rr = ww >> 3;
                const int cc = (ww & 7) << 2;
                *(float4*)&tile[jj * 1024 + rr * 32 + cc] =
                    *(const float4*)(tgt_p + (size_t)(tx * 32 + rr) * IMG_W + ty * 32 + cc);
            }
        }
        __syncthreads();

        for (int dxg = 0; dxg < 5; ++dxg) {
            float4 rf[4][4];
            bool rvalid[4];
            #pragma unroll
            for (int r = 0; r < 4; ++r) {
                const int di = dxg * 4 + r;
                const int bx = tx - (di - 8);
                rvalid[r] = (di <= 16) && ((unsigned)bx < 32u);
                if (rvalid[r]) {
                    const float* rb = ref_p + (size_t)(bx * 32 + prow) * IMG_W + by * 32 + pcol;
                    #pragma unroll
                    for (int i = 0; i < 4; ++i)
                        rf[r][i] = *(const float4*)(rb + (size_t)i * 8 * IMG_W);
                }
            }
            for (int dy = dyLo; dy <= dyHi; ++dy) {
                const int ty = by + dy;
                if ((unsigned)ty >= 32u) continue;      // wave-uniform
                const int tbase = (ty - tyBase) * 1024 + prow * 32 + pcol;
                float4 tv[4];
                #pragma unroll
                for (int i = 0; i < 4; ++i)
                    tv[i] = *(const float4*)&tile[tbase + i * 256];
                #pragma unroll
                for (int r = 0; r < 4; ++r) {
                    if (!rvalid[r]) continue;           // wave-uniform
                    float4 a = {0.f, 0.f, 0.f, 0.f};
                    #pragma unroll
                    for (int i = 0; i < 4; ++i) {
                        a.x += __builtin_fabsf(rf[r][i].x - tv[i].x);
                        a.y += __builtin_fabsf(rf[r][i].y - tv[i].y);
                        a.z += __builtin_fabsf(rf[r][i].z - tv[i].z);
                        a.w += __builtin_fabsf(rf[r][i].w - tv[i].w);
                    }
                    const float s = wave_sum63((a.x + a.y) + (a.z + a.w));
                    if (lane == 63) {
                        const int di = dxg * 4 + r;
                        const int bx = tx - (di - 8);
                        part[((size_t)plane * 1024 + bx * 32 + by) * 289 + di * 17 + (dy + 8)] = s;
                    }
                }
            }
        }
    }
}

// ============================================================================
// L0 phase 2: sum 12 plane-partials, first-min argmin over k (lex (dx,dy)).
// ============================================================================
__global__ __launch_bounds__(64) void hbma_l0_phase2(const float* __restrict__ part,
                                                     int2* __restrict__ best0) {
    const int by = blockIdx.x;
    const int bx = blockIdx.y;
    const int t = threadIdx.x;

    float bc = INF_F; int bk = 1 << 30;
    for (int k = t; k < 289; k += 64) {
        const int dx = k / 17 - 8, dy = k % 17 - 8;
        const int tx = bx + dx,    ty = by + dy;
        if ((unsigned)tx < 32u && (unsigned)ty < 32u) {
            float c = 0.f;
            #pragma unroll
            for (int p = 0; p < 12; ++p)
                c += part[((size_t)p * 1024 + bx * 32 + by) * 289 + k];
            if (c < bc) { bc = c; bk = k; }   // ascending k -> first-min kept
        }
    }
    #pragma unroll
    for (int o = 32; o > 0; o >>= 1) {
        const float oc = __shfl_down(bc, o, 64);
        const int   ok = __shfl_down(bk, o, 64);
        if (oc < bc || (oc == bc && ok < bk)) { bc = oc; bk = ok; }
    }
    if (t == 0) best0[bx * 32 + by] = make_int2(bx + bk / 17 - 8, by + bk % 17 - 8);
}

// ============================================================================
// L1 main: 4 WGs per parent (blockIdx.x = k-quarter q, 21 candidates each).
// 256 threads, same lane footprint + combine order as the R3 kernel (so the
// per-candidate sums are bit-identical). Costs -> part1[parent][child][81].
// 16k waves in flight hide L3 gather latency.
// ============================================================================
__global__ __launch_bounds__(256) void hbma_l1_main(const float* __restrict__ ref,
                                                    const float* __restrict__ tgt,
                                                    const int2* __restrict__ best0,
                                                    float* __restrict__ part1) {
    const int q   = blockIdx.x;  // k-quarter 0..3
    const int pby = blockIdx.y;  // 0..31
    const int pbx = blockIdx.z;  // 0..31
    const int parent = pbx * 32 + pby;
    const int t = threadIdx.x;
    const int lane = t & 63, w = t >> 6;

    __shared__ float partials[4][21][4];   // [child][local k][wave]

    const int2 pb = best0[parent];
    const int cx = 2 * pb.x, cy = 2 * pb.y;

    // thread footprint: 3 float4s of the 16x16x12 child block (same as R3)
    int off[3];
    #pragma unroll
    for (int i = 0; i < 3; ++i) {
        const int e4 = t + 256 * i;
        const int nc = e4 >> 6;
        const int ww = e4 & 63;
        off[i] = nc * SLICE + (ww >> 2) * IMG_W + ((ww & 3) << 2);
    }
    float4 rf[4][3];
    #pragma unroll
    for (int c = 0; c < 4; ++c) {
        const int bx = 2 * pbx + (c >> 1), by = 2 * pby + (c & 1);
        const int cb = (bx * 16) * IMG_W + by * 16;
        #pragma unroll
        for (int i = 0; i < 3; ++i)
            rf[c][i] = *(const float4*)(ref + cb + off[i]);
    }

    const int kbeg = q * 21;
    const int kcnt = min(81 - kbeg, 21);   // q=3 -> 18

    for (int j = 0; j < kcnt; ++j) {
        const int k  = kbeg + j;
        const int tx = cx + k / 9 - 4;
        const int ty = cy + k % 9 - 4;
        const bool valid = ((unsigned)tx < 64u) && ((unsigned)ty < 64u);
        const int ctx = min(max(tx, 0), 63);
        const int cty = min(max(ty, 0), 63);
        const float* tb = tgt + (ctx * 16) * IMG_W + cty * 16;

        float4 tv[3];
        #pragma unroll
        for (int i = 0; i < 3; ++i) tv[i] = *(const float4*)(tb + off[i]);

        #pragma unroll
        for (int c = 0; c < 4; ++c) {
            float4 a = {0.f, 0.f, 0.f, 0.f};
            #pragma unroll
            for (int i = 0; i < 3; ++i) {
                a.x += __builtin_fabsf(rf[c][i].x - tv[i].x);
                a.y += __builtin_fabsf(rf[c][i].y - tv[i].y);
                a.z += __builtin_fabsf(rf[c][i].z - tv[i].z);
                a.w += __builtin_fabsf(rf[c][i].w - tv[i].w);
            }
            const float s = wave_sum63((a.x + a.y) + (a.z + a.w));
            if (lane == 63) partials[c][j][w] = valid ? s : INF_F;
        }
    }
    __syncthreads();

    // combine 4 wave-partials (same order as R3: (w0+w1)+(w2+w3)) and publish
    for (int idx = t; idx < 4 * 21; idx += 256) {
        const int c = idx & 3, j = idx >> 2;
        const int k = kbeg + j;
        if (j < kcnt) {
            const float4 p4 = *(const float4*)&partials[c][j][0];
            part1[((size_t)parent * 4 + c) * 81 + k] = (p4.x + p4.y) + (p4.z + p4.w);
        }
    }
}

// ============================================================================
// L1 finish: per-child first-min argmin over 81 costs + MV write + gather.
// One WG (256 thr) per parent; wave w handles child w.
// ============================================================================
__global__ __launch_bounds__(256) void hbma_l1_finish(const float* __restrict__ tgt,
                                                      const int2* __restrict__ best0,
                                                      const float* __restrict__ part1,
                                                      float* __restrict__ out) {
    const int parent = blockIdx.x;       // 0..1023
    const int pbx = parent >> 5, pby = parent & 31;
    const int t = threadIdx.x;
    const int lane = t & 63, w = t >> 6;

    __shared__ int2 sbest[4];

    const int2 pb = best0[parent];
    const int cx = 2 * pb.x, cy = 2 * pb.y;

    {
        const int c = w;
        float bc = INF_F; int bk = 1 << 30;
        for (int k = lane; k < 81; k += 64) {
            const float cost = part1[((size_t)parent * 4 + c) * 81 + k];
            if (cost < bc) { bc = cost; bk = k; }
        }
        #pragma unroll
        for (int o = 32; o > 0; o >>= 1) {
            const float oc = __shfl_down(bc, o, 64);
            const int   ok = __shfl_down(bk, o, 64);
            if (oc < bc || (oc == bc && ok < bk)) { bc = oc; bk = ok; }
        }
        if (lane == 0) sbest[c] = make_int2(cx + bk / 9 - 4, cy + bk % 9 - 4);
    }
    __syncthreads();

    // motion vectors: out[0..32767] as [N=4][2][64][64] (same for all n)
    if (t < 32) {
        const int c = t >> 3, n = (t >> 1) & 3, ch = t & 1;
        const int bx = 2 * pbx + (c >> 1), by = 2 * pby + (c & 1);
        const int2 fb = sbest[c];
        out[((n * 2 + ch) * 64 + bx) * 64 + by] = (ch == 0) ? (float)(fb.x - bx) : (float)(fb.y - by);
    }

    // predicted frame gather for all 4 children
    float* pred = out + 32768;
    int off[3];
    #pragma unroll
    for (int i = 0; i < 3; ++i) {
        const int e4 = t + 256 * i;
        const int nc = e4 >> 6;
        const int ww = e4 & 63;
        off[i] = nc * SLICE + (ww >> 2) * IMG_W + ((ww & 3) << 2);
    }
    #pragma unroll
    for (int c = 0; c < 4; ++c) {
        const int bx = 2 * pbx + (c >> 1), by = 2 * pby + (c & 1);
        const int cb = (bx * 16) * IMG_W + by * 16;
        const int2 fb = sbest[c];
        const float* sb = tgt + (fb.x * 16) * IMG_W + fb.y * 16;
        #pragma unroll
        for (int i = 0; i < 3; ++i)
            *(float4*)(pred + cb + off[i]) = *(const float4*)(sb + off[i]);
    }
}

extern "C" void kernel_launch(void* const* d_in, const int* in_sizes, int n_in,
                              void* d_out, int out_size, void* d_ws, size_t ws_size,
                              hipStream_t stream) {
    const float* ref = (const float*)d_in[0];
    const float* tgt = (const float*)d_in[1];
    float* out = (float*)d_out;

    float* part  = (float*)d_ws;                                      // 14.2 MB (phase-1 partials)
    int2*  best0 = (int2*)((char*)d_ws + (size_t)WS_PART_FLOATS * 4); // 8 KB
    float* part1 = (float*)d_ws;   // aliases part (dead after phase2); 1.33 MB

    hbma_l0_phase1<<<dim3(32, 4, 12), 512, 0, stream>>>(ref, tgt, part);
    hbma_l0_phase2<<<dim3(32, 32), 64, 0, stream>>>(part, best0);
    hbma_l1_main<<<dim3(4, 32, 32), 256, 0, stream>>>(ref, tgt, best0, part1);
    hbma_l1_finish<<<dim3(1024), 256, 0, stream>>>(tgt, best0, part1, out);
}